// Round 11
// baseline (794.346 us; speedup 1.0000x reference)
//
#include <hip/hip_runtime.h>
#include <math.h>

typedef __bf16 bf16;
typedef __attribute__((ext_vector_type(4))) __bf16 bf16x4;
typedef __attribute__((ext_vector_type(8))) __bf16 bf16x8;
typedef __attribute__((ext_vector_type(4))) float f32x4;

#define T_STEPS 128
#define B_SZ    256
#define V_SZ    256
#define N_SZ    1024
#define NROWS   (T_STEPS * B_SZ)   // 32768
#define RSTR    68                 // step reduction stride (floats)
#define LSTR    17                 // loss reduction stride (floats)
#define NGRP    16                 // row groups (16 batch rows each)
#define NCB     16                 // col blocks per group (64 cols each)
#define ARRV    (NCB * 8)          // arrivals per group-step (per-wave arrive)

__device__ __forceinline__ float fast_tanh(float x) {
    float e = __expf(2.0f * x);
    return 1.0f - 2.0f / (e + 1.0f);   // exact at +-inf, no NaN
}

// ---------------- fp32 -> bf16 contiguous convert ----------------
__global__ void k_convert(const float* __restrict__ src, bf16* __restrict__ dst, int n) {
    int i = (blockIdx.x * blockDim.x + threadIdx.x) * 4;
    if (i < n) {
        float4 v = *(const float4*)(src + i);
        bf16x4 o;
        o.x = (bf16)v.x; o.y = (bf16)v.y; o.z = (bf16)v.z; o.w = (bf16)v.w;
        *(bf16x4*)(dst + i) = o;
    }
}

// ---------------- fp32 (R x C) -> bf16 transpose (C x R) ----------------
__global__ void k_transpose_cvt(const float* __restrict__ src, bf16* __restrict__ dst,
                                int R, int C) {
    __shared__ float tile[32][33];
    int c0 = blockIdx.x * 32;
    int r0 = blockIdx.y * 32;
    int tx = threadIdx.x & 31;
    int ty = threadIdx.x >> 5;   // 0..7
#pragma unroll
    for (int i = 0; i < 32; i += 8)
        tile[ty + i][tx] = src[(size_t)(r0 + ty + i) * C + c0 + tx];
    __syncthreads();
#pragma unroll
    for (int i = 0; i < 32; i += 8)
        dst[(size_t)(c0 + ty + i) * R + r0 + tx] = (bf16)tile[tx][ty + i];
}

// ---------------- persistent recurrence + fused Xproj seed + fused loss GEMM -------
// v2: ONE barrier per step. Per-wave poll (divergent-branch hold) and per-wave
// arrive (ARRV=128 per group-step). Step-MFMAs and loss-MFMAs share the a[] load
// and one LDS window; both epilogues in one post-barrier region; one vmcnt drain.
// No acquire fences anywhere => Wht/Wxt/Wot stay L2-hot for the whole kernel.
__global__ __launch_bounds__(512, 2) void k_rnn(
    const bf16* __restrict__ Xb,    // 32768 x 256 (bf16 inputs, t-major)
    const bf16* __restrict__ Wxt,   // 1024 x 256  = Wx^T
    const bf16* __restrict__ Wht,   // 1024 x 1024 = Wh^T
    const bf16* __restrict__ Wot,   // 256 x 1024  = Wo^T
    const float* __restrict__ bias,
    bf16* __restrict__ XH,          // 32768 x 1024 H states
    unsigned int* __restrict__ Lgu, // bf16-pair logits, slab layout [p][c][256][8]
    int* __restrict__ cnt)          // [NGRP * T_STEPS], zeroed
{
    __shared__ float red[8 * 16 * RSTR];   // 34.8 KB step K-reduce
    __shared__ float lred[8 * 16 * LSTR];  // 8.7 KB  loss K-reduce
    const int tid  = threadIdx.x;
    const int lane = tid & 63;
    const int w    = tid >> 6;        // 0..7
    const int quad = lane >> 4;
    const int l15  = lane & 15;
    const int g  = blockIdx.x >> 4;   // row group
    const int c  = blockIdx.x & 15;   // col block / vocab slab
    const int m0 = g * 16;
    const int n0 = c * 64;
    const int k0 = w * 128;           // K-slice for Wh / Wot GEMMs
    const int v0 = w * 32;            // K-slice for Xproj GEMM (V=256 / 8)
    int* gcnt = cnt + g * T_STEPS;

    // hoisted B fragments (compiler may re-load from hot L2 — fine, never invalidated)
    const bf16* Bp = Wht + (size_t)(n0 + l15) * N_SZ + k0 + quad * 8;
    bf16x8 b[4][4];
#pragma unroll
    for (int nt = 0; nt < 4; ++nt)
#pragma unroll
        for (int kc = 0; kc < 4; ++kc)
            b[nt][kc] = *(const bf16x8*)&Bp[(size_t)(nt * 16) * N_SZ + kc * 32];
    bf16x8 bx[4];
#pragma unroll
    for (int nt = 0; nt < 4; ++nt)
        bx[nt] = *(const bf16x8*)&Wxt[(size_t)(n0 + nt * 16 + l15) * V_SZ + v0 + quad * 8];
    bf16x8 bo[4];
#pragma unroll
    for (int kc = 0; kc < 4; ++kc)
        bo[kc] = *(const bf16x8*)&Wot[(size_t)(c * 16 + l15) * N_SZ + k0 + kc * 32 + quad * 8];

    const int orow = tid >> 5;           // 0..15 (wave w covers rows w*2, w*2+1)
    const int ocol = (tid & 31) * 2;     // 0..62
    const float bias0 = bias[n0 + ocol];
    const float bias1 = bias[n0 + ocol + 1];
    // loss epilogue mapping: 16 active lanes/wave, rows w*2+(lane>>3), vp = lane&7
    const int lrow = w * 2 + (lane >> 3);
    const int lvp  = lane & 7;
    unsigned int* XHu = (unsigned int*)XH;
    const f32x4 zz = {0.f, 0.f, 0.f, 0.f};

    // ---------------- t = 0: H_0 = tanh(Xproj_0 + bias) ----------------
    {
        bf16x8 ax = *(const bf16x8*)&Xb[(size_t)(m0 + l15) * V_SZ + v0 + quad * 8];
        f32x4 acc[4] = {zz, zz, zz, zz};
#pragma unroll
        for (int nt = 0; nt < 4; ++nt)
            acc[nt] = __builtin_amdgcn_mfma_f32_16x16x32_bf16(ax, bx[nt], acc[nt], 0, 0, 0);
#pragma unroll
        for (int nt = 0; nt < 4; ++nt)
#pragma unroll
            for (int r = 0; r < 4; ++r)
                red[(w * 16 + quad * 4 + r) * RSTR + nt * 16 + l15] = acc[nt][r];
        __syncthreads();
        float s0 = bias0, s1 = bias1;
#pragma unroll
        for (int w2 = 0; w2 < 8; ++w2) {
            float2 v = *(const float2*)&red[(w2 * 16 + orow) * RSTR + ocol];
            s0 += v.x; s1 += v.y;
        }
        bf16 r0 = (bf16)fast_tanh(s0);
        bf16 r1 = (bf16)fast_tanh(s1);
        unsigned int outw = (unsigned int)__builtin_bit_cast(unsigned short, r0)
                          | ((unsigned int)__builtin_bit_cast(unsigned short, r1) << 16);
        size_t oidx = (((size_t)0 * B_SZ + m0 + orow) * N_SZ + n0 + ocol) >> 1;
        __hip_atomic_store(&XHu[oidx], outw, __ATOMIC_RELAXED, __HIP_MEMORY_SCOPE_AGENT);
        asm volatile("s_waitcnt vmcnt(0)" ::: "memory");
        if (lane == 0)
            __hip_atomic_fetch_add(&gcnt[0], 1, __ATOMIC_RELAXED, __HIP_MEMORY_SCOPE_AGENT);
    }

    // ---------------- t = 1 .. 127 ----------------
    for (int t = 1; t < T_STEPS; ++t) {
        // Xb A-frag prefetch (read-only input, in flight through the poll)
        bf16x8 ax = *(const bf16x8*)&Xb[((size_t)t * B_SZ + m0 + l15) * V_SZ + v0 + quad * 8];

        // per-wave poll: divergent branch holds the whole wave until lane 0 exits
        if (lane == 0) {
            while (__hip_atomic_load(&gcnt[t - 1], __ATOMIC_RELAXED,
                                     __HIP_MEMORY_SCOPE_AGENT) < ARRV)
                __builtin_amdgcn_s_sleep(1);
        }

        // A fragments: 16 rows of H_{t-1} (first regular-load touch => fresh from L3)
        const bf16* Ap = XH + ((size_t)(t - 1) * B_SZ + m0 + l15) * N_SZ + k0 + quad * 8;
        bf16x8 a[4];
#pragma unroll
        for (int kc = 0; kc < 4; ++kc)
            a[kc] = *(const bf16x8*)&Ap[kc * 32];

        // step MFMAs: Xproj seed + A @ Wh^T-slice
        f32x4 acc[4] = {zz, zz, zz, zz};
#pragma unroll
        for (int nt = 0; nt < 4; ++nt)
            acc[nt] = __builtin_amdgcn_mfma_f32_16x16x32_bf16(ax, bx[nt], acc[nt], 0, 0, 0);
#pragma unroll
        for (int kc = 0; kc < 4; ++kc)
#pragma unroll
            for (int nt = 0; nt < 4; ++nt)
                acc[nt] = __builtin_amdgcn_mfma_f32_16x16x32_bf16(a[kc], b[nt][kc],
                                                                  acc[nt], 0, 0, 0);
        // loss MFMAs for plane t-1 (reuses a[])
        f32x4 lacc = zz;
#pragma unroll
        for (int kc = 0; kc < 4; ++kc)
            lacc = __builtin_amdgcn_mfma_f32_16x16x32_bf16(a[kc], bo[kc], lacc, 0, 0, 0);

        // both K-reduce writes in ONE window
#pragma unroll
        for (int nt = 0; nt < 4; ++nt)
#pragma unroll
            for (int r = 0; r < 4; ++r)
                red[(w * 16 + quad * 4 + r) * RSTR + nt * 16 + l15] = acc[nt][r];
#pragma unroll
        for (int r = 0; r < 4; ++r)
            lred[(w * 16 + quad * 4 + r) * LSTR + l15] = lacc[r];
        __syncthreads();   // the ONE barrier per step

        // step epilogue: reduce, tanh, publish (write-through dword)
        float s0 = bias0, s1 = bias1;
#pragma unroll
        for (int w2 = 0; w2 < 8; ++w2) {
            float2 v = *(const float2*)&red[(w2 * 16 + orow) * RSTR + ocol];
            s0 += v.x; s1 += v.y;
        }
        bf16 r0 = (bf16)fast_tanh(s0);
        bf16 r1 = (bf16)fast_tanh(s1);
        unsigned int outw = (unsigned int)__builtin_bit_cast(unsigned short, r0)
                          | ((unsigned int)__builtin_bit_cast(unsigned short, r1) << 16);
        size_t oidx = (((size_t)t * B_SZ + m0 + orow) * N_SZ + n0 + ocol) >> 1;
        __hip_atomic_store(&XHu[oidx], outw, __ATOMIC_RELAXED, __HIP_MEMORY_SCOPE_AGENT);

        // loss epilogue (balanced: 16 lanes per wave, own rows)
        if (lane < 16) {
            float sa = 0.f, sb = 0.f;
#pragma unroll
            for (int w2 = 0; w2 < 8; ++w2) {
                sa += lred[(w2 * 16 + lrow) * LSTR + lvp * 2];
                sb += lred[(w2 * 16 + lrow) * LSTR + lvp * 2 + 1];
            }
            bf16 pa = (bf16)sa, pb = (bf16)sb;
            unsigned int pw = (unsigned int)__builtin_bit_cast(unsigned short, pa)
                            | ((unsigned int)__builtin_bit_cast(unsigned short, pb) << 16);
            Lgu[(((size_t)(t - 1) * 16 + c) * B_SZ + m0 + lrow) * 8 + lvp] = pw;
        }

        // drain both stores, then per-wave arrive
        asm volatile("s_waitcnt vmcnt(0)" ::: "memory");
        if (lane == 0)
            __hip_atomic_fetch_add(&gcnt[t], 1, __ATOMIC_RELAXED, __HIP_MEMORY_SCOPE_AGENT);
    }

    // ---------------- tail: loss GEMM for plane 127 ----------------
    if (lane == 0) {
        while (__hip_atomic_load(&gcnt[T_STEPS - 1], __ATOMIC_RELAXED,
                                 __HIP_MEMORY_SCOPE_AGENT) < ARRV)
            __builtin_amdgcn_s_sleep(1);
    }
    {
        const bf16* Ap = XH + ((size_t)(T_STEPS - 1) * B_SZ + m0 + l15) * N_SZ + k0 + quad * 8;
        bf16x8 a[4];
#pragma unroll
        for (int kc = 0; kc < 4; ++kc)
            a[kc] = *(const bf16x8*)&Ap[kc * 32];
        f32x4 lacc = zz;
#pragma unroll
        for (int kc = 0; kc < 4; ++kc)
            lacc = __builtin_amdgcn_mfma_f32_16x16x32_bf16(a[kc], bo[kc], lacc, 0, 0, 0);
#pragma unroll
        for (int r = 0; r < 4; ++r)
            lred[(w * 16 + quad * 4 + r) * LSTR + l15] = lacc[r];
        __syncthreads();
        if (lane < 16) {
            float sa = 0.f, sb = 0.f;
#pragma unroll
            for (int w2 = 0; w2 < 8; ++w2) {
                sa += lred[(w2 * 16 + lrow) * LSTR + lvp * 2];
                sb += lred[(w2 * 16 + lrow) * LSTR + lvp * 2 + 1];
            }
            bf16 pa = (bf16)sa, pb = (bf16)sb;
            unsigned int pw = (unsigned int)__builtin_bit_cast(unsigned short, pa)
                            | ((unsigned int)__builtin_bit_cast(unsigned short, pb) << 16);
            Lgu[(((size_t)(T_STEPS - 1) * 16 + c) * B_SZ + m0 + lrow) * 8 + lvp] = pw;
        }
    }
}

// ---------------- final: log-softmax + weighted-label loss over bf16 logits --------
// 256 blocks x 256 threads (4 waves); block handles 128 rows, wave 32 rows.
// Logits layout: [plane][cslab 16][row-in-plane 256][16 vocab] bf16.
__global__ __launch_bounds__(256) void k_lred(
    const bf16* __restrict__ Lg,
    const float* __restrict__ labels,
    const float* __restrict__ ob,
    float* __restrict__ out)
{
    __shared__ float bt[4];
    const int tid  = threadIdx.x;
    const int lane = tid & 63;
    const int w    = tid >> 6;       // 0..3
    const int cs   = lane >> 2;      // vocab slab 0..15
    const int vi   = (lane & 3) * 4; // offset in slab
    const float4 ob4 = *(const float4*)&ob[cs * 16 + vi];

    float wtot = 0.f;
    for (int i = 0; i < 32; ++i) {
        int row  = blockIdx.x * 128 + w * 32 + i;
        int p    = row >> 8;
        int brow = row & 255;
        bf16x4 lv = *(const bf16x4*)&Lg[(((size_t)p * 16 + cs) * B_SZ + brow) * 16 + vi];
        float l0 = (float)lv.x + ob4.x;
        float l1 = (float)lv.y + ob4.y;
        float l2 = (float)lv.z + ob4.z;
        float l3 = (float)lv.w + ob4.w;
        float mx = fmaxf(fmaxf(l0, l1), fmaxf(l2, l3));
#pragma unroll
        for (int s = 1; s < 64; s <<= 1)
            mx = fmaxf(mx, __shfl_xor(mx, s, 64));
        float sume = __expf(l0 - mx) + __expf(l1 - mx) + __expf(l2 - mx) + __expf(l3 - mx);
        const float4 lb = *(const float4*)&labels[(size_t)row * V_SZ + cs * 16 + vi];
        float labs = lb.x + lb.y + lb.z + lb.w;
        float labv = lb.x * l0 + lb.y * l1 + lb.z * l2 + lb.w * l3;
#pragma unroll
        for (int s = 1; s < 64; s <<= 1) {
            sume += __shfl_xor(sume, s, 64);
            labs += __shfl_xor(labs, s, 64);
            labv += __shfl_xor(labv, s, 64);
        }
        float lse = mx + __logf(sume);
        wtot += labs * lse - labv;
    }
    if (lane == 0) bt[w] = wtot;
    __syncthreads();
    if (tid == 0)
        atomicAdd(out, (bt[0] + bt[1] + bt[2] + bt[3]) * (1.0f / (float)NROWS));
}

extern "C" void kernel_launch(void* const* d_in, const int* in_sizes, int n_in,
                              void* d_out, int out_size, void* d_ws, size_t ws_size,
                              hipStream_t stream)
{
    const float* inputs  = (const float*)d_in[0];
    const float* labels  = (const float*)d_in[1];
    const float* weights = (const float*)d_in[2];
    const float* bias    = (const float*)d_in[3];
    const float* out_w   = (const float*)d_in[4];
    const float* out_b   = (const float*)d_in[5];
    float* out = (float*)d_out;

    char* ws = (char*)d_ws;
    bf16* XH  = (bf16*)ws;  ws += (size_t)NROWS * N_SZ * 2;   // 64 MB H states
    bf16* Xb  = (bf16*)ws;  ws += (size_t)NROWS * V_SZ * 2;   // 16 MB
    bf16* Lg  = (bf16*)ws;  ws += (size_t)NROWS * V_SZ * 2;   // 16 MB bf16 logits
    bf16* Wxt = (bf16*)ws;  ws += (size_t)N_SZ * V_SZ * 2;    // 0.5 MB (Wx^T)
    bf16* Wht = (bf16*)ws;  ws += (size_t)N_SZ * N_SZ * 2;    // 2 MB   (Wh^T)
    bf16* Wot = (bf16*)ws;  ws += (size_t)V_SZ * N_SZ * 2;    // 0.5 MB (Wo^T)
    int*  cnt = (int*)ws;   ws += (size_t)NGRP * T_STEPS * 4; // 8 KB sync counters

    hipMemsetAsync(out, 0, sizeof(float), stream);
    hipMemsetAsync(cnt, 0, (size_t)NGRP * T_STEPS * 4, stream);

    k_convert<<<dim3(NROWS * V_SZ / 1024), 256, 0, stream>>>(inputs, Xb, NROWS * V_SZ);
    k_transpose_cvt<<<dim3(N_SZ / 32, V_SZ / 32), 256, 0, stream>>>(weights, Wxt, V_SZ, N_SZ);
    k_transpose_cvt<<<dim3(N_SZ / 32, N_SZ / 32), 256, 0, stream>>>(
        weights + (size_t)V_SZ * N_SZ, Wht, N_SZ, N_SZ);
    k_transpose_cvt<<<dim3(V_SZ / 32, N_SZ / 32), 256, 0, stream>>>(out_w, Wot, N_SZ, V_SZ);

    k_rnn<<<dim3(NGRP * NCB), 512, 0, stream>>>(Xb, Wxt, Wht, Wot, bias, XH,
                                                (unsigned int*)Lg, cnt);

    k_lred<<<dim3(NROWS / 128), 256, 0, stream>>>(Lg, labels, out_b, out);
}

// Round 12
// 503.952 us; speedup vs baseline: 1.5762x; 1.5762x over previous
//
#include <hip/hip_runtime.h>
#include <math.h>

typedef __bf16 bf16;
typedef __attribute__((ext_vector_type(4))) __bf16 bf16x4;
typedef __attribute__((ext_vector_type(8))) __bf16 bf16x8;
typedef __attribute__((ext_vector_type(4))) float f32x4;

#define T_STEPS 128
#define B_SZ    256
#define V_SZ    256
#define N_SZ    1024
#define NROWS   (T_STEPS * B_SZ)   // 32768
#define RSTR    68                 // step reduction stride (floats)
#define LSTR    17                 // loss reduction stride (floats)
#define NGRP    16                 // row groups (16 batch rows each)
#define NCB     16                 // col blocks per group (64 cols each)

__device__ __forceinline__ float fast_tanh(float x) {
    float e = __expf(2.0f * x);
    return 1.0f - 2.0f / (e + 1.0f);   // exact at +-inf, no NaN
}

// ---------------- fp32 -> bf16 contiguous convert ----------------
__global__ void k_convert(const float* __restrict__ src, bf16* __restrict__ dst, int n) {
    int i = (blockIdx.x * blockDim.x + threadIdx.x) * 4;
    if (i < n) {
        float4 v = *(const float4*)(src + i);
        bf16x4 o;
        o.x = (bf16)v.x; o.y = (bf16)v.y; o.z = (bf16)v.z; o.w = (bf16)v.w;
        *(bf16x4*)(dst + i) = o;
    }
}

// ---------------- fp32 (R x C) -> bf16 transpose (C x R) ----------------
__global__ void k_transpose_cvt(const float* __restrict__ src, bf16* __restrict__ dst,
                                int R, int C) {
    __shared__ float tile[32][33];
    int c0 = blockIdx.x * 32;
    int r0 = blockIdx.y * 32;
    int tx = threadIdx.x & 31;
    int ty = threadIdx.x >> 5;   // 0..7
#pragma unroll
    for (int i = 0; i < 32; i += 8)
        tile[ty + i][tx] = src[(size_t)(r0 + ty + i) * C + c0 + tx];
    __syncthreads();
#pragma unroll
    for (int i = 0; i < 32; i += 8)
        dst[(size_t)(c0 + ty + i) * R + r0 + tx] = (bf16)tile[tx][ty + i];
}

// ---------------- persistent recurrence + fused Xproj seed + fused loss GEMM -------
// v3: R9's block-level sync (1 atomic + 1 poller per block per step — per-wave
// arrive in R10 caused 8x same-line atomic contention, +2.4 us/step) combined
// with R10's merged epilogue (loss MFMAs share a[]; red+lred in one LDS window).
// 3 barriers/step: poll-release, post-reduce-write, pre-arrive (protects red/lred
// reuse AND orders all waves' vmcnt drains before the single arrive).
// No acquire fences anywhere => Wht/Wxt/Wot stay L2-hot for the whole kernel.
__global__ __launch_bounds__(512, 2) void k_rnn(
    const bf16* __restrict__ Xb,    // 32768 x 256 (bf16 inputs, t-major)
    const bf16* __restrict__ Wxt,   // 1024 x 256  = Wx^T
    const bf16* __restrict__ Wht,   // 1024 x 1024 = Wh^T
    const bf16* __restrict__ Wot,   // 256 x 1024  = Wo^T
    const float* __restrict__ bias,
    bf16* __restrict__ XH,          // 32768 x 1024 H states
    unsigned int* __restrict__ Lgu, // bf16-pair logits, slab layout [p][c][256][8]
    int* __restrict__ cnt)          // [NGRP * T_STEPS], zeroed
{
    __shared__ float red[8 * 16 * RSTR];   // 34.8 KB step K-reduce
    __shared__ float lred[8 * 16 * LSTR];  // 8.7 KB  loss K-reduce
    const int tid  = threadIdx.x;
    const int lane = tid & 63;
    const int w    = tid >> 6;        // 0..7
    const int quad = lane >> 4;
    const int l15  = lane & 15;
    const int g  = blockIdx.x >> 4;   // row group
    const int c  = blockIdx.x & 15;   // col block / vocab slab
    const int m0 = g * 16;
    const int n0 = c * 64;
    const int k0 = w * 128;           // K-slice for Wh / Wot GEMMs
    const int v0 = w * 32;            // K-slice for Xproj GEMM (V=256 / 8)
    int* gcnt = cnt + g * T_STEPS;

    // hoisted B fragments (compiler may re-load from hot L2 — fine, never invalidated)
    const bf16* Bp = Wht + (size_t)(n0 + l15) * N_SZ + k0 + quad * 8;
    bf16x8 b[4][4];
#pragma unroll
    for (int nt = 0; nt < 4; ++nt)
#pragma unroll
        for (int kc = 0; kc < 4; ++kc)
            b[nt][kc] = *(const bf16x8*)&Bp[(size_t)(nt * 16) * N_SZ + kc * 32];
    bf16x8 bx[4];
#pragma unroll
    for (int nt = 0; nt < 4; ++nt)
        bx[nt] = *(const bf16x8*)&Wxt[(size_t)(n0 + nt * 16 + l15) * V_SZ + v0 + quad * 8];
    bf16x8 bo[4];
#pragma unroll
    for (int kc = 0; kc < 4; ++kc)
        bo[kc] = *(const bf16x8*)&Wot[(size_t)(c * 16 + l15) * N_SZ + k0 + kc * 32 + quad * 8];

    const int orow = tid >> 5;           // 0..15
    const int ocol = (tid & 31) * 2;     // 0..62
    const float bias0 = bias[n0 + ocol];
    const float bias1 = bias[n0 + ocol + 1];
    // loss epilogue mapping: 16 active lanes/wave, rows w*2+(lane>>3), vp = lane&7
    const int lrow = w * 2 + (lane >> 3);
    const int lvp  = lane & 7;
    unsigned int* XHu = (unsigned int*)XH;
    const f32x4 zz = {0.f, 0.f, 0.f, 0.f};

    // ---------------- t = 0: H_0 = tanh(Xproj_0 + bias) ----------------
    {
        bf16x8 ax = *(const bf16x8*)&Xb[(size_t)(m0 + l15) * V_SZ + v0 + quad * 8];
        f32x4 acc[4] = {zz, zz, zz, zz};
#pragma unroll
        for (int nt = 0; nt < 4; ++nt)
            acc[nt] = __builtin_amdgcn_mfma_f32_16x16x32_bf16(ax, bx[nt], acc[nt], 0, 0, 0);
#pragma unroll
        for (int nt = 0; nt < 4; ++nt)
#pragma unroll
            for (int r = 0; r < 4; ++r)
                red[(w * 16 + quad * 4 + r) * RSTR + nt * 16 + l15] = acc[nt][r];
        __syncthreads();
        float s0 = bias0, s1 = bias1;
#pragma unroll
        for (int w2 = 0; w2 < 8; ++w2) {
            float2 v = *(const float2*)&red[(w2 * 16 + orow) * RSTR + ocol];
            s0 += v.x; s1 += v.y;
        }
        bf16 r0 = (bf16)fast_tanh(s0);
        bf16 r1 = (bf16)fast_tanh(s1);
        unsigned int outw = (unsigned int)__builtin_bit_cast(unsigned short, r0)
                          | ((unsigned int)__builtin_bit_cast(unsigned short, r1) << 16);
        size_t oidx = (((size_t)0 * B_SZ + m0 + orow) * N_SZ + n0 + ocol) >> 1;
        __hip_atomic_store(&XHu[oidx], outw, __ATOMIC_RELAXED, __HIP_MEMORY_SCOPE_AGENT);
        asm volatile("s_waitcnt vmcnt(0)" ::: "memory");
        __syncthreads();
        if (tid == 0)
            __hip_atomic_fetch_add(&gcnt[0], 1, __ATOMIC_RELAXED, __HIP_MEMORY_SCOPE_AGENT);
    }

    // ---------------- t = 1 .. 127 ----------------
    for (int t = 1; t < T_STEPS; ++t) {
        // Xb A-frag prefetch (read-only input, in flight through the poll)
        bf16x8 ax = *(const bf16x8*)&Xb[((size_t)t * B_SZ + m0 + l15) * V_SZ + v0 + quad * 8];

        // block-level poll: ONE poller + ONE arrive atomic per block per step
        if (tid == 0) {
            while (__hip_atomic_load(&gcnt[t - 1], __ATOMIC_RELAXED,
                                     __HIP_MEMORY_SCOPE_AGENT) < NCB)
                __builtin_amdgcn_s_sleep(1);
        }
        __syncthreads();

        // A fragments: 16 rows of H_{t-1} (first regular-load touch => fresh from L3)
        const bf16* Ap = XH + ((size_t)(t - 1) * B_SZ + m0 + l15) * N_SZ + k0 + quad * 8;
        bf16x8 a[4];
#pragma unroll
        for (int kc = 0; kc < 4; ++kc)
            a[kc] = *(const bf16x8*)&Ap[kc * 32];

        // step MFMAs: Xproj seed + A @ Wh^T-slice
        f32x4 acc[4] = {zz, zz, zz, zz};
#pragma unroll
        for (int nt = 0; nt < 4; ++nt)
            acc[nt] = __builtin_amdgcn_mfma_f32_16x16x32_bf16(ax, bx[nt], acc[nt], 0, 0, 0);
#pragma unroll
        for (int kc = 0; kc < 4; ++kc)
#pragma unroll
            for (int nt = 0; nt < 4; ++nt)
                acc[nt] = __builtin_amdgcn_mfma_f32_16x16x32_bf16(a[kc], b[nt][kc],
                                                                  acc[nt], 0, 0, 0);
        // loss MFMAs for plane t-1 (reuses a[])
        f32x4 lacc = zz;
#pragma unroll
        for (int kc = 0; kc < 4; ++kc)
            lacc = __builtin_amdgcn_mfma_f32_16x16x32_bf16(a[kc], bo[kc], lacc, 0, 0, 0);

        // both K-reduce writes in ONE window
#pragma unroll
        for (int nt = 0; nt < 4; ++nt)
#pragma unroll
            for (int r = 0; r < 4; ++r)
                red[(w * 16 + quad * 4 + r) * RSTR + nt * 16 + l15] = acc[nt][r];
#pragma unroll
        for (int r = 0; r < 4; ++r)
            lred[(w * 16 + quad * 4 + r) * LSTR + l15] = lacc[r];
        __syncthreads();

        // step epilogue: reduce, tanh, publish (write-through dword)
        float s0 = bias0, s1 = bias1;
#pragma unroll
        for (int w2 = 0; w2 < 8; ++w2) {
            float2 v = *(const float2*)&red[(w2 * 16 + orow) * RSTR + ocol];
            s0 += v.x; s1 += v.y;
        }
        bf16 r0 = (bf16)fast_tanh(s0);
        bf16 r1 = (bf16)fast_tanh(s1);
        unsigned int outw = (unsigned int)__builtin_bit_cast(unsigned short, r0)
                          | ((unsigned int)__builtin_bit_cast(unsigned short, r1) << 16);
        size_t oidx = (((size_t)t * B_SZ + m0 + orow) * N_SZ + n0 + ocol) >> 1;
        __hip_atomic_store(&XHu[oidx], outw, __ATOMIC_RELAXED, __HIP_MEMORY_SCOPE_AGENT);

        // loss epilogue (16 lanes per wave, own rows)
        if (lane < 16) {
            float sa = 0.f, sb = 0.f;
#pragma unroll
            for (int w2 = 0; w2 < 8; ++w2) {
                sa += lred[(w2 * 16 + lrow) * LSTR + lvp * 2];
                sb += lred[(w2 * 16 + lrow) * LSTR + lvp * 2 + 1];
            }
            bf16 pa = (bf16)sa, pb = (bf16)sb;
            unsigned int pw = (unsigned int)__builtin_bit_cast(unsigned short, pa)
                            | ((unsigned int)__builtin_bit_cast(unsigned short, pb) << 16);
            Lgu[(((size_t)(t - 1) * 16 + c) * B_SZ + m0 + lrow) * 8 + lvp] = pw;
        }

        // drain stores (per-wave), then barrier so ALL waves drained + epilogue
        // LDS reads done (protects red/lred reuse), then single arrive.
        asm volatile("s_waitcnt vmcnt(0)" ::: "memory");
        __syncthreads();
        if (tid == 0)
            __hip_atomic_fetch_add(&gcnt[t], 1, __ATOMIC_RELAXED, __HIP_MEMORY_SCOPE_AGENT);
    }

    // ---------------- tail: loss GEMM for plane 127 ----------------
    if (tid == 0) {
        while (__hip_atomic_load(&gcnt[T_STEPS - 1], __ATOMIC_RELAXED,
                                 __HIP_MEMORY_SCOPE_AGENT) < NCB)
            __builtin_amdgcn_s_sleep(1);
    }
    __syncthreads();
    {
        const bf16* Ap = XH + ((size_t)(T_STEPS - 1) * B_SZ + m0 + l15) * N_SZ + k0 + quad * 8;
        bf16x8 a[4];
#pragma unroll
        for (int kc = 0; kc < 4; ++kc)
            a[kc] = *(const bf16x8*)&Ap[kc * 32];
        f32x4 lacc = zz;
#pragma unroll
        for (int kc = 0; kc < 4; ++kc)
            lacc = __builtin_amdgcn_mfma_f32_16x16x32_bf16(a[kc], bo[kc], lacc, 0, 0, 0);
#pragma unroll
        for (int r = 0; r < 4; ++r)
            lred[(w * 16 + quad * 4 + r) * LSTR + l15] = lacc[r];
        __syncthreads();
        if (lane < 16) {
            float sa = 0.f, sb = 0.f;
#pragma unroll
            for (int w2 = 0; w2 < 8; ++w2) {
                sa += lred[(w2 * 16 + lrow) * LSTR + lvp * 2];
                sb += lred[(w2 * 16 + lrow) * LSTR + lvp * 2 + 1];
            }
            bf16 pa = (bf16)sa, pb = (bf16)sb;
            unsigned int pw = (unsigned int)__builtin_bit_cast(unsigned short, pa)
                            | ((unsigned int)__builtin_bit_cast(unsigned short, pb) << 16);
            Lgu[(((size_t)(T_STEPS - 1) * 16 + c) * B_SZ + m0 + lrow) * 8 + lvp] = pw;
        }
    }
}

// ---------------- final: log-softmax + weighted-label loss over bf16 logits --------
// 256 blocks x 256 threads (4 waves); block handles 128 rows, wave 32 rows.
// Logits layout: [plane][cslab 16][row-in-plane 256][16 vocab] bf16.
__global__ __launch_bounds__(256) void k_lred(
    const bf16* __restrict__ Lg,
    const float* __restrict__ labels,
    const float* __restrict__ ob,
    float* __restrict__ out)
{
    __shared__ float bt[4];
    const int tid  = threadIdx.x;
    const int lane = tid & 63;
    const int w    = tid >> 6;       // 0..3
    const int cs   = lane >> 2;      // vocab slab 0..15
    const int vi   = (lane & 3) * 4; // offset in slab
    const float4 ob4 = *(const float4*)&ob[cs * 16 + vi];

    float wtot = 0.f;
    for (int i = 0; i < 32; ++i) {
        int row  = blockIdx.x * 128 + w * 32 + i;
        int p    = row >> 8;
        int brow = row & 255;
        bf16x4 lv = *(const bf16x4*)&Lg[(((size_t)p * 16 + cs) * B_SZ + brow) * 16 + vi];
        float l0 = (float)lv.x + ob4.x;
        float l1 = (float)lv.y + ob4.y;
        float l2 = (float)lv.z + ob4.z;
        float l3 = (float)lv.w + ob4.w;
        float mx = fmaxf(fmaxf(l0, l1), fmaxf(l2, l3));
#pragma unroll
        for (int s = 1; s < 64; s <<= 1)
            mx = fmaxf(mx, __shfl_xor(mx, s, 64));
        float sume = __expf(l0 - mx) + __expf(l1 - mx) + __expf(l2 - mx) + __expf(l3 - mx);
        const float4 lb = *(const float4*)&labels[(size_t)row * V_SZ + cs * 16 + vi];
        float labs = lb.x + lb.y + lb.z + lb.w;
        float labv = lb.x * l0 + lb.y * l1 + lb.z * l2 + lb.w * l3;
#pragma unroll
        for (int s = 1; s < 64; s <<= 1) {
            sume += __shfl_xor(sume, s, 64);
            labs += __shfl_xor(labs, s, 64);
            labv += __shfl_xor(labv, s, 64);
        }
        float lse = mx + __logf(sume);
        wtot += labs * lse - labv;
    }
    if (lane == 0) bt[w] = wtot;
    __syncthreads();
    if (tid == 0)
        atomicAdd(out, (bt[0] + bt[1] + bt[2] + bt[3]) * (1.0f / (float)NROWS));
}

extern "C" void kernel_launch(void* const* d_in, const int* in_sizes, int n_in,
                              void* d_out, int out_size, void* d_ws, size_t ws_size,
                              hipStream_t stream)
{
    const float* inputs  = (const float*)d_in[0];
    const float* labels  = (const float*)d_in[1];
    const float* weights = (const float*)d_in[2];
    const float* bias    = (const float*)d_in[3];
    const float* out_w   = (const float*)d_in[4];
    const float* out_b   = (const float*)d_in[5];
    float* out = (float*)d_out;

    char* ws = (char*)d_ws;
    bf16* XH  = (bf16*)ws;  ws += (size_t)NROWS * N_SZ * 2;   // 64 MB H states
    bf16* Xb  = (bf16*)ws;  ws += (size_t)NROWS * V_SZ * 2;   // 16 MB
    bf16* Lg  = (bf16*)ws;  ws += (size_t)NROWS * V_SZ * 2;   // 16 MB bf16 logits
    bf16* Wxt = (bf16*)ws;  ws += (size_t)N_SZ * V_SZ * 2;    // 0.5 MB (Wx^T)
    bf16* Wht = (bf16*)ws;  ws += (size_t)N_SZ * N_SZ * 2;    // 2 MB   (Wh^T)
    bf16* Wot = (bf16*)ws;  ws += (size_t)V_SZ * N_SZ * 2;    // 0.5 MB (Wo^T)
    int*  cnt = (int*)ws;   ws += (size_t)NGRP * T_STEPS * 4; // 8 KB sync counters

    hipMemsetAsync(out, 0, sizeof(float), stream);
    hipMemsetAsync(cnt, 0, (size_t)NGRP * T_STEPS * 4, stream);

    k_convert<<<dim3(NROWS * V_SZ / 1024), 256, 0, stream>>>(inputs, Xb, NROWS * V_SZ);
    k_transpose_cvt<<<dim3(N_SZ / 32, V_SZ / 32), 256, 0, stream>>>(weights, Wxt, V_SZ, N_SZ);
    k_transpose_cvt<<<dim3(N_SZ / 32, N_SZ / 32), 256, 0, stream>>>(
        weights + (size_t)V_SZ * N_SZ, Wht, N_SZ, N_SZ);
    k_transpose_cvt<<<dim3(V_SZ / 32, N_SZ / 32), 256, 0, stream>>>(out_w, Wot, N_SZ, V_SZ);

    k_rnn<<<dim3(NGRP * NCB), 512, 0, stream>>>(Xb, Wxt, Wht, Wot, bias, XH,
                                                (unsigned int*)Lg, cnt);

    k_lred<<<dim3(NROWS / 128), 256, 0, stream>>>(Lg, labels, out_b, out);
}